// Round 12
// baseline (201.568 us; speedup 1.0000x reference)
//
#include <hip/hip_runtime.h>
#include <math.h>

#define N_NODES 200000
#define N_VAR   112000
#define N_EDGES 3200000
#define CAP     64            // max neighbors consumed per node (== wave size)

// ---- two-level counting-sort params ----
#define NFINE    512          // fine dst-range buckets
#define PSZ_F    391          // nodes per bucket (512*391 = 200192 >= 200000)
#define FCAP     7168         // per-bucket edge capacity (mean 6250, ~11.6 sigma slack)
#define BIN_CHUNK 8192        // edges per k_bin block (391 blocks; measured best)
#define NB_BIN   391          // ceil(3.2e6/8192)
#define NB_L1    12500        // 200000 / 16 nodes per block

typedef int v4i __attribute__((ext_vector_type(4)));

// ---------- phase A: bin edges into 512 dst-range buckets + folded setup ----------
// Packed entry: (dst_local<<18 | src), dst_local<391 (9b), src<2^18.
// 8192-edge chunks + wave-shuffle scan (2 barriers) + fused Wc/bc fold.
__global__ void __launch_bounds__(512) k_bin(const int* __restrict__ src,
                                             const int* __restrict__ dst,
                                             int* __restrict__ bins,
                                             int* __restrict__ bcnt,
                                             const float* __restrict__ W2,
                                             const float* __restrict__ b2,
                                             const float* __restrict__ Wfc,
                                             const float* __restrict__ bfc,
                                             float* __restrict__ Wc,
                                             float* __restrict__ bc) {
    __shared__ int hist[NFINE];
    __shared__ int seg[NFINE];
    __shared__ int gb[NFINE];
    __shared__ int cur[NFINE];
    __shared__ int wsum[8];
    __shared__ int stg[BIN_CHUNK];
    __shared__ unsigned short stgb[BIN_CHUNK];
    int tid = threadIdx.x;
    int lane = tid & 63, wid = tid >> 6;
    hist[tid] = 0;
    __syncthreads();

    int base = blockIdx.x * BIN_CHUNK;
    int pk[4][4];
    int bk[4][4];
    bool val[4];
    #pragma unroll
    for (int i = 0; i < 4; ++i) {
        int e4 = base + (i * 512 + tid) * 4;
        val[i] = (e4 < N_EDGES);       // N_EDGES % 4 == 0 -> full quad if valid
        if (val[i]) {
            v4i d = __builtin_nontemporal_load((const v4i*)(dst + e4));
            v4i s = __builtin_nontemporal_load((const v4i*)(src + e4));
            int dd[4] = {d.x, d.y, d.z, d.w};
            int ss[4] = {s.x, s.y, s.z, s.w};
            #pragma unroll
            for (int q = 0; q < 4; ++q) {
                int bb2 = dd[q] / PSZ_F;               // const div -> magic mul
                int dl = dd[q] - bb2 * PSZ_F;          // < 391 (9 bits)
                pk[i][q] = (dl << 18) | ss[q];
                bk[i][q] = bb2;
                atomicAdd(&hist[bb2], 1);
            }
        }
    }
    __syncthreads();

    // wave-shuffle inclusive scan over 512 entries (2 barriers total)
    int h = hist[tid];
    int inc = h;
    #pragma unroll
    for (int d = 1; d < 64; d <<= 1) {
        int t = __shfl_up(inc, d);
        if (lane >= d) inc += t;
    }
    if (lane == 63) wsum[wid] = inc;
    __syncthreads();
    int pre = 0, tot = 0;
    #pragma unroll
    for (int k = 0; k < 8; ++k) {
        int s = wsum[k];
        pre += (k < wid) ? s : 0;
        tot += s;
    }
    int ex = pre + inc - h;
    seg[tid] = ex;
    cur[tid] = ex;
    gb[tid]  = atomicAdd(&bcnt[tid], h);
    __syncthreads();

    // compact into stg by bucket
    #pragma unroll
    for (int i = 0; i < 4; ++i) {
        if (val[i]) {
            #pragma unroll
            for (int q = 0; q < 4; ++q) {
                int p = atomicAdd(&cur[bk[i][q]], 1);
                stg[p]  = pk[i][q];
                stgb[p] = (unsigned short)bk[i][q];
            }
        }
    }
    __syncthreads();

    // coalesced copy-out: per-bucket contiguous runs (avg 16 edges = 64B)
    for (int i = tid; i < tot; i += 512) {
        int bb2 = stgb[i];
        int pos = gb[bb2] + (i - seg[bb2]);
        if (pos < FCAP)
            bins[(size_t)bb2 * FCAP + pos] = stg[i];
    }

    // folded setup (identical f64 math to original k_setup)
    int b = blockIdx.x;
    if (b < 8) {
        int e = b * 512 + tid;             // 4096 entries
        int j = e >> 6, l2 = e & 63;
        double acc = 0.0;
        for (int m = 0; m < 64; ++m)
            acc += (double)W2[j * 64 + m] * (double)Wfc[m * 64 + l2];
        Wc[e] = (float)acc;
    } else if (b == 8 && tid < 64) {
        double acc = (double)bfc[tid];
        for (int m = 0; m < 64; ++m)
            acc += (double)b2[m] * (double)Wfc[m * 64 + tid];
        bc[tid] = (float)acc;
    }
}

// ---------- phase B: per-bucket counting sort -> CSR rows + packed cnt2 + xdc ----------
// CSR: bucket edge base = wave-scan over capped bucket counts; rows unpadded,
// concatenated. cnt2[v] = (global_row_ptr << 7) | min(deg,127). Write-out is a
// pure streaming masked copy (rowid array deleted; LDS 47->35KB -> 4 blocks/CU).
__global__ void __launch_bounds__(512) k_sort(const int* __restrict__ bins,
                                              const int* __restrict__ bcnt,
                                              const float2* __restrict__ x2,
                                              int* __restrict__ cnt2,
                                              float4* __restrict__ xdc,
                                              int* __restrict__ buf2) {
    __shared__ int hist[NFINE];
    __shared__ int off[NFINE];
    __shared__ int cur[NFINE];
    __shared__ int wsum[8];
    __shared__ int ebs;
    __shared__ int sorted_pk[FCAP];      // 28.7 KB
    int tid = threadIdx.x;
    int lane = tid & 63, wid = tid >> 6;
    int b = blockIdx.x;

    // CSR bucket base: exclusive scan of capped counts across all 512 buckets
    int ec = bcnt[tid];
    if (ec > FCAP) ec = FCAP;
    int incE = ec;
    #pragma unroll
    for (int d = 1; d < 64; d <<= 1) {
        int t = __shfl_up(incE, d);
        if (lane >= d) incE += t;
    }
    if (lane == 63) wsum[wid] = incE;
    __syncthreads();
    int preE = 0;
    #pragma unroll
    for (int k = 0; k < 8; ++k)
        preE += (k < wid) ? wsum[k] : 0;
    if (tid == b) ebs = preE + incE - ec;    // exclusive prefix for bucket b
    hist[tid] = 0;
    __syncthreads();
    int ebase = ebs;
    int nb = bcnt[b];
    if (nb > FCAP) nb = FCAP;
    const int* __restrict__ bp = bins + (size_t)b * FCAP;

    for (int i = tid; i < nb; i += 512)
        atomicAdd(&hist[bp[i] >> 18], 1);
    __syncthreads();

    int h = hist[tid];

    // within-bucket node scan -> exclusive row offsets
    int inc = h;
    #pragma unroll
    for (int d = 1; d < 64; d <<= 1) {
        int t = __shfl_up(inc, d);
        if (lane >= d) inc += t;
    }
    if (lane == 63) wsum[wid] = inc;
    __syncthreads();
    int pre = 0;
    #pragma unroll
    for (int k = 0; k < 8; ++k)
        pre += (k < wid) ? wsum[k] : 0;
    int ex = pre + inc - h;
    off[tid] = ex;
    cur[tid] = ex;

    // packed cnt2 + xdc (deg capped at 127: identical for any realizable degree)
    int vg = b * PSZ_F + tid;
    if (tid < PSZ_F && vg < N_NODES) {
        int ct = (h < 127) ? h : 127;
        cnt2[vg] = ((ebase + ex) << 7) | ct;
        float dvv = rsqrtf((float)ct + 1.0f);
        float2 xv = x2[vg];
        xdc[vg] = make_float4(xv.x * dvv, xv.y * dvv, dvv, 0.0f);
    }
    __syncthreads();

    // LDS reorder: dst-sorted packed edges
    for (int i = tid; i < nb; i += 512) {
        int pkv = bp[i];
        int p = atomicAdd(&cur[pkv >> 18], 1);
        sorted_pk[p] = pkv;
    }
    __syncthreads();

    // streaming CSR write-out (fully monotone coalesced, no gaps)
    for (int i = tid; i < nb; i += 512)
        buf2[ebase + i] = sorted_pk[i] & 0x3FFFF;
}

// ---------- layer 1 -- wave-per-4-nodes, CSR rows, predicated gather ----------
__global__ void __launch_bounds__(256, 4) k_l1a(const int* __restrict__ cnt2,
                                                const int* __restrict__ buf2,
                                                const float4* __restrict__ xdc,
                                                float4* __restrict__ zn) {
    __shared__ __align__(16) float2 pb2[4][64];   // per-wave stage (2KB)
    int w = threadIdx.x >> 6, l = threadIdx.x & 63;
    float2* __restrict__ pbw = &pb2[w][0];
    int v0 = blockIdx.x * 16 + w;          // wave w owns v0, v0+4, v0+8, v0+12
    int q0 = __builtin_amdgcn_readfirstlane(cnt2[v0]);
    int q1 = __builtin_amdgcn_readfirstlane(cnt2[v0 + 4]);
    int q2 = __builtin_amdgcn_readfirstlane(cnt2[v0 + 8]);
    int q3 = __builtin_amdgcn_readfirstlane(cnt2[v0 + 12]);

    // hoisted loads: predicated CSR row gathers + selfs, all in flight up front
    int nn[4];
    float2 g[4];
    float4 zs[4];
    #pragma unroll
    for (int it = 0; it < 4; ++it) {
        int v = v0 + it * 4;
        int q = (it == 0) ? q0 : (it == 1) ? q1 : (it == 2) ? q2 : q3;
        int c = q & 127;
        int n = (c < CAP) ? c : CAP;
        int rp = ((unsigned)q) >> 7;
        nn[it] = n;
        int ridx = v;                      // lanes >= n: self (harmless, L2-hot)
        if (l < n) ridx = __builtin_nontemporal_load(buf2 + rp + l);
        g[it]  = *(const float2*)&xdc[ridx];  // (x*dv, y*dv), 8B
        zs[it] = xdc[v];                      // self incl. dv (uniform)
    }

    #pragma unroll
    for (int it = 0; it < 4; ++it) {
        int v = v0 + it * 4;
        int n = nn[it];
        float4 self = zs[it];
        float dv = self.z;
        pbw[l] = g[it];                    // wave-private stage, no barrier

        float ax = self.x, ay = self.y;
        float bx = 0.0f,   by = 0.0f;
        int j = 0;
        for (; j + 16 <= n; j += 16) {
            float4 t0 = *(const float4*)&pbw[j +  0];   // (p0.x p0.y p1.x p1.y)
            float4 t1 = *(const float4*)&pbw[j +  2];
            float4 t2 = *(const float4*)&pbw[j +  4];
            float4 t3 = *(const float4*)&pbw[j +  6];
            float4 t4 = *(const float4*)&pbw[j +  8];
            float4 t5 = *(const float4*)&pbw[j + 10];
            float4 t6 = *(const float4*)&pbw[j + 12];
            float4 t7 = *(const float4*)&pbw[j + 14];
            ax += t0.x; ay += t0.y;  bx += t0.z; by += t0.w;
            ax += t1.x; ay += t1.y;  bx += t1.z; by += t1.w;
            ax += t2.x; ay += t2.y;  bx += t2.z; by += t2.w;
            ax += t3.x; ay += t3.y;  bx += t3.z; by += t3.w;
            ax += t4.x; ay += t4.y;  bx += t4.z; by += t4.w;
            ax += t5.x; ay += t5.y;  bx += t5.z; by += t5.w;
            ax += t6.x; ay += t6.y;  bx += t6.z; by += t6.w;
            ax += t7.x; ay += t7.y;  bx += t7.z; by += t7.w;
        }
        for (; j + 8 <= n; j += 8) {
            float4 t0 = *(const float4*)&pbw[j + 0];
            float4 t1 = *(const float4*)&pbw[j + 2];
            float4 t2 = *(const float4*)&pbw[j + 4];
            float4 t3 = *(const float4*)&pbw[j + 6];
            ax += t0.x; ay += t0.y;  bx += t0.z; by += t0.w;
            ax += t1.x; ay += t1.y;  bx += t1.z; by += t1.w;
            ax += t2.x; ay += t2.y;  bx += t2.z; by += t2.w;
            ax += t3.x; ay += t3.y;  bx += t3.z; by += t3.w;
        }
        for (; j < n; ++j) {
            float2 qv = pbw[j];
            ax += qv.x; ay += qv.y;
        }
        if (l == 0)
            zn[v] = make_float4((ax + bx) * dv, (ay + by) * dv, dv, 0.0f);
    }
}

// ---------- layer 2 + folded fc -- R10 structure, CSR rows ----------
__global__ void __launch_bounds__(256, 4) k_l2(const int* __restrict__ cnt2,
                                               const int* __restrict__ buf2,
                                               const float4* __restrict__ zn,
                                               const float* __restrict__ W1,
                                               const float* __restrict__ b1,
                                               const float* __restrict__ Wc,
                                               const float* __restrict__ bc,
                                               float* __restrict__ out) {
    __shared__ __align__(16) float4 pb[4][64];   // per-wave neighbor broadcast buf (4KB)
    __shared__ __align__(16) float  avs[4][64];  // per-wave Av broadcast buf (1KB)
    int w = threadIdx.x >> 6, l = threadIdx.x & 63;
    float4* __restrict__ pbw = &pb[w][0];
    float*  __restrict__ avw = &avs[w][0];
    float wc[64];
    #pragma unroll
    for (int jv = 0; jv < 64; ++jv)
        wc[jv] = Wc[jv * 64 + l];
    float w1a = W1[l], w1b = W1[64 + l], bb = b1[l];
    float bcl = bc[l];
    int v0 = blockIdx.x * 16 + w;          // wave w owns v0, v0+4, v0+8, v0+12
    int q0 = __builtin_amdgcn_readfirstlane(cnt2[v0]);
    int q1 = __builtin_amdgcn_readfirstlane(cnt2[v0 + 4]);
    int q2 = __builtin_amdgcn_readfirstlane(cnt2[v0 + 8]);
    int q3 = __builtin_amdgcn_readfirstlane(cnt2[v0 + 12]);

    // hoisted loads: predicated CSR row gathers + selfs, all in flight up front
    int nn[4], cc[4];
    float4 p[4], zs[4];
    #pragma unroll
    for (int it = 0; it < 4; ++it) {
        int v = v0 + it * 4;
        int q = (it == 0) ? q0 : (it == 1) ? q1 : (it == 2) ? q2 : q3;
        int c = q & 127;
        int n = (c < CAP) ? c : CAP;
        int rp = ((unsigned)q) >> 7;
        nn[it] = n;
        cc[it] = c;
        int ridx = v;                      // lanes >= n: self (harmless, L2-hot)
        if (l < n) ridx = __builtin_nontemporal_load(buf2 + rp + l);
        p[it]  = zn[ridx];                 // per-lane gather: lane i = neighbor i
        zs[it] = zn[v];                    // self (uniform)
    }

    #pragma unroll
    for (int it = 0; it < 4; ++it) {
        int v = v0 + it * 4;
        int n = nn[it];
        float dv = rsqrtf((float)cc[it] + 1.0f);
        float4 zss = zs[it];

        pbw[l] = p[it];                    // stage this node's neighbors (wave-private)

        float acc0 = fmaxf(fmaf(zss.x, w1a, fmaf(zss.y, w1b, bb)), 0.0f) * zss.z;
        float acc1 = 0.0f;
        int j = 0;
        for (; j + 8 <= n; j += 8) {
            float4 r0 = pbw[j+0], r1 = pbw[j+1], r2 = pbw[j+2], r3 = pbw[j+3];
            float4 r4 = pbw[j+4], r5 = pbw[j+5], r6 = pbw[j+6], r7 = pbw[j+7];
            float h0 = fmaxf(fmaf(r0.x, w1a, fmaf(r0.y, w1b, bb)), 0.0f) * r0.z;
            float h1 = fmaxf(fmaf(r1.x, w1a, fmaf(r1.y, w1b, bb)), 0.0f) * r1.z;
            float h2 = fmaxf(fmaf(r2.x, w1a, fmaf(r2.y, w1b, bb)), 0.0f) * r2.z;
            float h3 = fmaxf(fmaf(r3.x, w1a, fmaf(r3.y, w1b, bb)), 0.0f) * r3.z;
            float h4 = fmaxf(fmaf(r4.x, w1a, fmaf(r4.y, w1b, bb)), 0.0f) * r4.z;
            float h5 = fmaxf(fmaf(r5.x, w1a, fmaf(r5.y, w1b, bb)), 0.0f) * r5.z;
            float h6 = fmaxf(fmaf(r6.x, w1a, fmaf(r6.y, w1b, bb)), 0.0f) * r6.z;
            float h7 = fmaxf(fmaf(r7.x, w1a, fmaf(r7.y, w1b, bb)), 0.0f) * r7.z;
            acc0 += (h0 + h1) + (h2 + h3);
            acc1 += (h4 + h5) + (h6 + h7);
        }
        for (; j + 4 <= n; j += 4) {
            float4 r0 = pbw[j+0], r1 = pbw[j+1], r2 = pbw[j+2], r3 = pbw[j+3];
            float h0 = fmaxf(fmaf(r0.x, w1a, fmaf(r0.y, w1b, bb)), 0.0f) * r0.z;
            float h1 = fmaxf(fmaf(r1.x, w1a, fmaf(r1.y, w1b, bb)), 0.0f) * r1.z;
            float h2 = fmaxf(fmaf(r2.x, w1a, fmaf(r2.y, w1b, bb)), 0.0f) * r2.z;
            float h3 = fmaxf(fmaf(r3.x, w1a, fmaf(r3.y, w1b, bb)), 0.0f) * r3.z;
            acc0 += (h0 + h1) + (h2 + h3);
        }
        for (; j < n; ++j) {
            float4 r0 = pbw[j];
            acc1 += fmaxf(fmaf(r0.x, w1a, fmaf(r0.y, w1b, bb)), 0.0f) * r0.z;
        }
        float Av = (acc0 + acc1) * dv;     // lane l holds channel l's aggregate

        avw[l] = Av;                       // stage Av (wave-private)

        // FC: identical accumulation grouping to R3-R11 -> same FP result.
        float t0 = 0.0f, t1 = 0.0f, t2 = 0.0f, t3 = 0.0f;
        #pragma unroll
        for (int jj = 0; jj < 64; jj += 4) {
            float4 a4 = *(const float4*)&avw[jj];      // same-addr ds_read_b128
            t0 = fmaf(a4.x, wc[jj + 0], t0);
            t1 = fmaf(a4.y, wc[jj + 1], t1);
            t2 = fmaf(a4.z, wc[jj + 2], t2);
            t3 = fmaf(a4.w, wc[jj + 3], t3);
        }
        float t = ((t0 + t1) + (t2 + t3)) + bcl;
        __builtin_nontemporal_store(rintf(fmaxf(t, 0.0f)), out + v * 64 + l);
    }
}

// ---------------- launch ----------------

extern "C" void kernel_launch(void* const* d_in, const int* in_sizes, int n_in,
                              void* d_out, int out_size, void* d_ws, size_t ws_size,
                              hipStream_t stream) {
    const float* x    = (const float*)d_in[0];
    const int*   ei   = (const int*)  d_in[1];
    const float* W1   = (const float*)d_in[2];
    const float* b1   = (const float*)d_in[3];
    const float* W2   = (const float*)d_in[4];
    const float* b2   = (const float*)d_in[5];
    const float* Wfc  = (const float*)d_in[6];
    const float* bfc  = (const float*)d_in[7];
    float* out = (float*)d_out;

    const int* src = ei;
    const int* dst = ei + N_EDGES;

    // workspace layout (bytes), 16-aligned; total 70,420,736 (unchanged size)
    //   cnt2 [0, 800000)            written k_sort, read l1a/l2  (rp<<7 | deg)
    //   xdc  [800000, 4000000)      written k_sort, read l1a
    //   bins [4000000, 18680064)    written k_bin, read k_sort
    //   bcnt [18680064, 18682112)   memset, k_bin atomics, k_sort read
    //   zn   [15204096, 18404096)   written l1a (bins dead), read l2
    //   buf2 [19204096, 32004096)   CSR edges, 12.8MB (was 51.2 padded)
    //   Wc/bc[70404096, 70420736)   written k_bin blocks 0..8, read l2
    char* ws = (char*)d_ws;
    int*    cnt2   = (int*)   (ws + 0);
    float4* xdc    = (float4*)(ws + 800000);
    int*    bins   = (int*)   (ws + 4000000);
    int*    bcnt   = (int*)   (ws + 18680064);
    float4* zn     = (float4*)(ws + 15204096);   // aliases dead bins tail
    int*    buf2   = (int*)   (ws + 19204096);
    float*  Wc     = (float*) (ws + 70404096);
    float*  bc     = (float*) (ws + 70420480);

    hipMemsetAsync(bcnt, 0, NFINE * sizeof(int), stream);
    k_bin  <<<NB_BIN, 512, 0, stream>>>(src, dst, bins, bcnt, W2, b2, Wfc, bfc, Wc, bc);
    k_sort <<<NFINE, 512, 0, stream>>>(bins, bcnt, (const float2*)x, cnt2, xdc, buf2);
    k_l1a  <<<NB_L1, 256, 0, stream>>>(cnt2, buf2, xdc, zn);
    k_l2   <<<N_VAR / 16, 256, 0, stream>>>(cnt2, buf2, zn, W1, b1, Wc, bc, out);
}